// Round 4
// baseline (512.759 us; speedup 1.0000x reference)
//
#include <hip/hip_runtime.h>
#include <hip/hip_bf16.h>
#include <math.h>

#define NCH 32
#define NBIN 512
#define SLICE 4096

typedef unsigned short ushort_t;
typedef unsigned int uint_t;
typedef unsigned char uchar_t;

static __device__ __forceinline__ float bf2f(ushort_t b) {
    return __uint_as_float(((uint_t)b) << 16);
}
static __device__ __forceinline__ ushort_t f2bf(float f) {
    __hip_bfloat16 h = __float2bfloat16(f);
    return *reinterpret_cast<ushort_t*>(&h);
}

using f32x2 = __attribute__((ext_vector_type(2))) float;

// ===========================================================================
// Round-17: zero-global-atomic CSR grouping.
//   r16 post-mortem: k_uv_hist WRITE 65.5 MB = 16 MB data + 1.6M x 32B
//   atomic sectors; both r13 apply (1.6M atomics, 87us) and r16 hist
//   (1.6M atomics, 86us) sit at ~18.6 G atomics/s -> every E-atomic pass
//   costs ~86us. The CSR build had TWO such passes (deg hist + cursors).
//   Fix: 512 coarse bins (<=256 nodes each). count(LDS hist, plain stores)
//   -> hierarchical scan over cnt[bin][slice] -> binscatter (LDS cursors,
//   packed payload (tgt<<8)|loc, contiguous runs). Stats/apply process one
//   bin per block: u staged in LDS, apply accumulates into an LDS fp32
//   out-tile (LDS atomics) and stores coalesced. ZERO global atomics in
//   the whole main path.
// ===========================================================================

// --- per-node uh,vh (bf16) + vq (fp8 e4m3) ---------------------------------
__global__ __launch_bounds__(256) void k_uv(
    const float* __restrict__ x, const float* __restrict__ W,
    ushort_t* __restrict__ uh, ushort_t* __restrict__ vh,
    uchar_t* __restrict__ vq, int N)
{
    __shared__ float At[NCH * NCH];   // At[k*32+c] = W[c][k] - W[c][32+k]
    __shared__ float Bt[NCH * NCH];   // Bt[k*32+c] = W[c][32+k]
    for (int i = threadIdx.x; i < NCH * NCH; i += 256) {
        const int k = i >> 5, c = i & 31;
        const float w1 = W[c * 64 + k];
        const float w2 = W[c * 64 + 32 + k];
        At[i] = w1 - w2;
        Bt[i] = w2;
    }
    __syncthreads();

    const int n = blockIdx.x * 8 + (threadIdx.x >> 5);
    const int c = threadIdx.x & 31;
    if (n >= N) return;
    const float xc = x[(size_t)n * NCH + c];
    float su = 0.f, sv = 0.f;
#pragma unroll
    for (int k = 0; k < NCH; ++k) {
        const float xk = __shfl(xc, k, 32);
        su = fmaf(At[k * 32 + c], xk, su);
        sv = fmaf(Bt[k * 32 + c], xk, sv);
    }
    uh[(size_t)n * NCH + c] = f2bf(su);
    vh[(size_t)n * NCH + c] = f2bf(sv);
    vq[(size_t)n * NCH + c] =
        (uchar_t)(__builtin_amdgcn_cvt_pk_fp8_f32(sv, sv, 0, false) & 0xFF);
}

// --- count: per-slice LDS histogram over 512 bins, plain coalesced stores --
__global__ __launch_bounds__(256) void k_count(
    const int* __restrict__ srci, uint_t* __restrict__ cnt, int E, int NSB)
{
    __shared__ int h[NBIN];
    for (int i = threadIdx.x; i < NBIN; i += 256) h[i] = 0;
    __syncthreads();
    const int k = blockIdx.x;
    const int lo = k * SLICE;
    const int hi = (lo + SLICE < E) ? lo + SLICE : E;
    for (int e = lo + threadIdx.x; e < hi; e += 256)
        atomicAdd(&h[srci[e] / NSB], 1);
    __syncthreads();
    for (int b = threadIdx.x; b < NBIN; b += 256)
        cnt[(size_t)k * NBIN + b] = (uint_t)h[b];
}

// --- scan stage 1: block sums over scan-order (bin-major) ------------------
__global__ __launch_bounds__(256) void k_cbsum(
    const uint_t* __restrict__ cnt, int* __restrict__ bsum, int L, int NBLK)
{
    const int i = blockIdx.x * 256 + threadIdx.x;
    int d = 0;
    if (i < L) {
        const int b = i / NBLK, kk = i - b * NBLK;
        d = (int)cnt[(size_t)kk * NBIN + b];
    }
#pragma unroll
    for (int off = 32; off > 0; off >>= 1) d += __shfl_down(d, off, 64);
    __shared__ int w[4];
    if ((threadIdx.x & 63) == 0) w[threadIdx.x >> 6] = d;
    __syncthreads();
    if (threadIdx.x == 0) bsum[blockIdx.x] = w[0] + w[1] + w[2] + w[3];
}

// --- scan stage 2: single-block exclusive scan of block sums (NB<=1024) ----
__global__ __launch_bounds__(1024) void k_scan_boff2(
    int* __restrict__ bsum, int NB)
{
    const int t = threadIdx.x;
    const int lane = t & 63;
    const int s = (t < NB) ? bsum[t] : 0;
    int v = s;
#pragma unroll
    for (int off = 1; off < 64; off <<= 1) {
        int nv = __shfl_up(v, off, 64);
        if (lane >= off) v += nv;
    }
    __shared__ int ws[16];
    __shared__ int wp[16];
    if (lane == 63) ws[t >> 6] = v;
    __syncthreads();
    if (t == 0) {
        int a = 0;
#pragma unroll
        for (int w = 0; w < 16; ++w) { wp[w] = a; a += ws[w]; }
    }
    __syncthreads();
    if (t < NB) bsum[t] = wp[t >> 6] + v - s;
}

// --- scan stage 3: per-element exclusive offsets, linear coalesced write ---
__global__ __launch_bounds__(256) void k_cwrite(
    const uint_t* __restrict__ cnt, const int* __restrict__ boff,
    uint_t* __restrict__ scn, int L, int NBLK)
{
    const int i = blockIdx.x * 256 + threadIdx.x;
    const int t = threadIdx.x;
    const int lane = t & 63;
    int d = 0;
    if (i < L) {
        const int b = i / NBLK, kk = i - b * NBLK;
        d = (int)cnt[(size_t)kk * NBIN + b];
    }
    int v = d;
#pragma unroll
    for (int off = 1; off < 64; off <<= 1) {
        int nv = __shfl_up(v, off, 64);
        if (lane >= off) v += nv;
    }
    __shared__ int ws[4];
    __shared__ int wp[4];
    if (lane == 63) ws[t >> 6] = v;
    __syncthreads();
    if (t == 0) {
        int a = 0;
#pragma unroll
        for (int w = 0; w < 4; ++w) { wp[w] = a; a += ws[w]; }
    }
    __syncthreads();
    if (i < L) scn[i] = (uint_t)(boff[blockIdx.x] + wp[t >> 6] + v - d);
}

// --- binscatter: LDS cursors from scan, packed payload (tgt<<8)|loc --------
__global__ __launch_bounds__(256) void k_binscatter(
    const int* __restrict__ srci, const int* __restrict__ tgti,
    const uint_t* __restrict__ scn, uint_t* __restrict__ pay,
    int E, int NSB, int NBLK)
{
    __shared__ int cur[NBIN];
    const int k = blockIdx.x;
    for (int b = threadIdx.x; b < NBIN; b += 256)
        cur[b] = (int)scn[(size_t)b * NBLK + k];
    __syncthreads();
    const int lo = k * SLICE;
    const int hi = (lo + SLICE < E) ? lo + SLICE : E;
    for (int e = lo + threadIdx.x; e < hi; e += 256) {
        const int s = srci[e], t = tgti[e];
        const int b = s / NSB, loc = s - b * NSB;
        const int pos = atomicAdd(&cur[b], 1);
        pay[pos] = ((uint_t)t << 8) | (uint_t)loc;
    }
}

// --- stats: one bin per 2 blocks, u staged in LDS, per-edge y via fp8 v ----
__global__ __launch_bounds__(256) void k_stats_bin(
    const ushort_t* __restrict__ uh, const uchar_t* __restrict__ vq,
    const uint_t* __restrict__ scn, const uint_t* __restrict__ pay,
    float* __restrict__ partials, int N, int NSB, int NBLK, int E)
{
    const uint_t* __restrict__ uh32 = (const uint_t*)uh;
    const ushort_t* __restrict__ vq16 = (const ushort_t*)vq;
    __shared__ uint_t uL[256 * 16];   // bin's u rows (<=256 nodes x 16 words)

    const int bin = blockIdx.x >> 1;
    const int chunk = blockIdx.x & 1;
    const int lo_n = bin * NSB;
    const int nsb_l = (lo_n + NSB <= N) ? NSB : (N - lo_n);
    for (int i = threadIdx.x; i < nsb_l * 16; i += 256)
        uL[i] = uh32[(size_t)lo_n * 16 + i];
    __syncthreads();

    const int e0 = (int)scn[(size_t)bin * NBLK];
    const int e1 = (bin == NBIN - 1) ? E : (int)scn[(size_t)(bin + 1) * NBLK];

    const int l = threadIdx.x & 15;
    const int grp = threadIdx.x >> 4;          // 16 groups/block
    const int gidx = chunk * 16 + grp;         // 32 groups/bin

    float s0 = 0.f, s1 = 0.f, q0 = 0.f, q1 = 0.f;
    int e = e0 + gidx;
    for (; e + 96 < e1; e += 128) {
        const uint_t pa = pay[e], pb = pay[e + 32], pc = pay[e + 64], pd = pay[e + 96];
        const ushort_t va = vq16[(size_t)(pa >> 8) * 16 + l];
        const ushort_t vb = vq16[(size_t)(pb >> 8) * 16 + l];
        const ushort_t vc = vq16[(size_t)(pc >> 8) * 16 + l];
        const ushort_t vd = vq16[(size_t)(pd >> 8) * 16 + l];
        const uint_t P[4] = {pa, pb, pc, pd};
        const ushort_t V[4] = {va, vb, vc, vd};
#pragma unroll
        for (int u = 0; u < 4; ++u) {
            const f32x2 vf = __builtin_amdgcn_cvt_pk_f32_fp8((int)V[u], false);
            const uint_t U = uL[(P[u] & 255) * 16 + l];
            const float y0 = bf2f((ushort_t)(U & 0xFFFF)) + vf.x;
            const float y1 = bf2f((ushort_t)(U >> 16)) + vf.y;
            s0 += y0; q0 = fmaf(y0, y0, q0);
            s1 += y1; q1 = fmaf(y1, y1, q1);
        }
    }
    for (; e < e1; e += 32) {
        const uint_t p = pay[e];
        const f32x2 vf = __builtin_amdgcn_cvt_pk_f32_fp8(
            (int)vq16[(size_t)(p >> 8) * 16 + l], false);
        const uint_t U = uL[(p & 255) * 16 + l];
        const float y0 = bf2f((ushort_t)(U & 0xFFFF)) + vf.x;
        const float y1 = bf2f((ushort_t)(U >> 16)) + vf.y;
        s0 += y0; q0 = fmaf(y0, y0, q0);
        s1 += y1; q1 = fmaf(y1, y1, q1);
    }

    __shared__ float sL[16][32];
    __shared__ float qL[16][32];
    sL[grp][2 * l + 0] = s0;
    sL[grp][2 * l + 1] = s1;
    qL[grp][2 * l + 0] = q0;
    qL[grp][2 * l + 1] = q1;
    __syncthreads();
    if (threadIdx.x < 32) {
        float a = 0.f;
#pragma unroll
        for (int r = 0; r < 16; ++r) a += sL[r][threadIdx.x];
        partials[(size_t)blockIdx.x * 64 + threadIdx.x] = a;
    } else if (threadIdx.x < 64) {
        const int cc = threadIdx.x - 32;
        float a = 0.f;
#pragma unroll
        for (int r = 0; r < 16; ++r) a += qL[r][cc];
        partials[(size_t)blockIdx.x * 64 + 32 + cc] = a;
    }
}

// --- combine partials -> BN affine a,b -------------------------------------
__global__ __launch_bounds__(256) void k_finalize(
    const float* __restrict__ partials, int nblocks,
    const float* __restrict__ gamma, const float* __restrict__ beta,
    float* __restrict__ ab, float invE)
{
    __shared__ float acc[4][64];
    const int vtx = threadIdx.x & 63, chunk = threadIdx.x >> 6;
    float s = 0.f;
    for (int r = chunk; r < nblocks; r += 4) s += partials[(size_t)r * 64 + vtx];
    acc[chunk][vtx] = s;
    __syncthreads();
    if (threadIdx.x < 64) acc[0][vtx] = acc[0][vtx] + acc[1][vtx] + acc[2][vtx] + acc[3][vtx];
    __syncthreads();
    if (threadIdx.x < 32) {
        const int c = threadIdx.x;
        float mean = acc[0][c] * invE;
        float var  = acc[0][32 + c] * invE - mean * mean;
        float rstd = rsqrtf(var + 1e-5f);
        float a = gamma[c] * rstd;
        ab[c] = a; ab[32 + c] = beta[c] - mean * a;
    }
}

// --- apply: one bin per block; LDS fp32 out-tile; coalesced final store ----
__global__ __launch_bounds__(512) void k_apply_bin(
    const ushort_t* __restrict__ uh, const ushort_t* __restrict__ vh,
    const uint_t* __restrict__ scn, const uint_t* __restrict__ pay,
    const float* __restrict__ ab, float* __restrict__ out,
    int N, int NSB, int NBLK, int E)
{
    const uint_t* __restrict__ uh32 = (const uint_t*)uh;
    const uint_t* __restrict__ vh32 = (const uint_t*)vh;
    __shared__ uint_t uL[256 * 16];     // 16 KB
    __shared__ float  oL[256 * 32];     // 32 KB fp32 out-tile

    const int bin = blockIdx.x;
    const int lo_n = bin * NSB;
    const int nsb_l = (lo_n + NSB <= N) ? NSB : (N - lo_n);
    for (int i = threadIdx.x; i < nsb_l * 16; i += 512)
        uL[i] = uh32[(size_t)lo_n * 16 + i];
    for (int i = threadIdx.x; i < nsb_l * 32; i += 512)
        oL[i] = 0.f;
    __syncthreads();

    const int e0 = (int)scn[(size_t)bin * NBLK];
    const int e1 = (bin == NBIN - 1) ? E : (int)scn[(size_t)(bin + 1) * NBLK];

    const int l = threadIdx.x & 15;
    const int grp = threadIdx.x >> 4;          // 32 groups/block
    const float a0 = ab[2 * l + 0], a1 = ab[2 * l + 1];
    const float b0 = ab[32 + 2 * l + 0], b1 = ab[32 + 2 * l + 1];

    int e = e0 + grp;
    for (; e + 96 < e1; e += 128) {
        const uint_t pa = pay[e], pb = pay[e + 32], pc = pay[e + 64], pd = pay[e + 96];
        const uint_t Va = vh32[(size_t)(pa >> 8) * 16 + l];
        const uint_t Vb = vh32[(size_t)(pb >> 8) * 16 + l];
        const uint_t Vc = vh32[(size_t)(pc >> 8) * 16 + l];
        const uint_t Vd = vh32[(size_t)(pd >> 8) * 16 + l];
        const uint_t P[4] = {pa, pb, pc, pd};
        const uint_t V[4] = {Va, Vb, Vc, Vd};
#pragma unroll
        for (int u = 0; u < 4; ++u) {
            const int loc = (int)(P[u] & 255);
            const uint_t U = uL[loc * 16 + l];
            const float y0 = bf2f((ushort_t)(U & 0xFFFF)) + bf2f((ushort_t)(V[u] & 0xFFFF));
            const float y1 = bf2f((ushort_t)(U >> 16))    + bf2f((ushort_t)(V[u] >> 16));
            float z0 = fmaf(a0, y0, b0);
            float z1 = fmaf(a1, y1, b1);
            z0 = (z0 > 0.f) ? z0 : (__expf(z0) - 1.0f);
            z1 = (z1 > 0.f) ? z1 : (__expf(z1) - 1.0f);
            atomicAdd(&oL[loc * 32 + 2 * l + 0], z0);
            atomicAdd(&oL[loc * 32 + 2 * l + 1], z1);
        }
    }
    for (; e < e1; e += 32) {
        const uint_t p = pay[e];
        const int loc = (int)(p & 255);
        const uint_t V = vh32[(size_t)(p >> 8) * 16 + l];
        const uint_t U = uL[loc * 16 + l];
        const float y0 = bf2f((ushort_t)(U & 0xFFFF)) + bf2f((ushort_t)(V & 0xFFFF));
        const float y1 = bf2f((ushort_t)(U >> 16))    + bf2f((ushort_t)(V >> 16));
        float z0 = fmaf(a0, y0, b0);
        float z1 = fmaf(a1, y1, b1);
        z0 = (z0 > 0.f) ? z0 : (__expf(z0) - 1.0f);
        z1 = (z1 > 0.f) ? z1 : (__expf(z1) - 1.0f);
        atomicAdd(&oL[loc * 32 + 2 * l + 0], z0);
        atomicAdd(&oL[loc * 32 + 2 * l + 1], z1);
    }
    __syncthreads();
    for (int i = threadIdx.x; i < nsb_l * 32; i += 512)
        out[(size_t)lo_n * 32 + i] = oL[i];
}

// ===========================================================================
// FALLBACK (round-1 proven path) — only if guards fail
// ===========================================================================
__global__ __launch_bounds__(256) void k_stats_hist(
    const float* __restrict__ x,
    const int* __restrict__ srci, const int* __restrict__ tgti,
    const float* __restrict__ W,
    float* __restrict__ partials, int E)
{
    float sum[NCH], ssq[NCH];
#pragma unroll
    for (int c = 0; c < NCH; ++c) { sum[c] = 0.f; ssq[c] = 0.f; }
    const int stride = gridDim.x * blockDim.x;
    for (int e = blockIdx.x * blockDim.x + threadIdx.x; e < E; e += stride) {
        const int s = srci[e], t = tgti[e];
        const float4* ps = (const float4*)(x + (size_t)s * NCH);
        const float4* pt = (const float4*)(x + (size_t)t * NCH);
        float xs[NCH], dx[NCH];
#pragma unroll
        for (int i = 0; i < 8; ++i) {
            float4 a = ps[i], bb = pt[i];
            xs[4*i+0] = a.x; xs[4*i+1] = a.y; xs[4*i+2] = a.z; xs[4*i+3] = a.w;
            dx[4*i+0] = bb.x - a.x; dx[4*i+1] = bb.y - a.y;
            dx[4*i+2] = bb.z - a.z; dx[4*i+3] = bb.w - a.w;
        }
#pragma unroll
        for (int c = 0; c < NCH; ++c) {
            const float* wr = W + c * 64;
            float y = 0.f;
#pragma unroll
            for (int k = 0; k < NCH; ++k) y = fmaf(wr[k], xs[k], y);
#pragma unroll
            for (int k = 0; k < NCH; ++k) y = fmaf(wr[32 + k], dx[k], y);
            sum[c] += y;
            ssq[c] = fmaf(y, y, ssq[c]);
        }
    }
#pragma unroll
    for (int c = 0; c < NCH; ++c) {
#pragma unroll
        for (int off = 32; off > 0; off >>= 1) {
            sum[c] += __shfl_down(sum[c], off);
            ssq[c] += __shfl_down(ssq[c], off);
        }
    }
    __shared__ float red[4][64];
    const int lane = threadIdx.x & 63, wave = threadIdx.x >> 6;
    if (lane == 0) {
#pragma unroll
        for (int c = 0; c < NCH; ++c) { red[wave][c] = sum[c]; red[wave][NCH+c] = ssq[c]; }
    }
    __syncthreads();
    if (threadIdx.x < 64)
        partials[(size_t)blockIdx.x * 64 + threadIdx.x] =
            red[0][threadIdx.x] + red[1][threadIdx.x] + red[2][threadIdx.x] + red[3][threadIdx.x];
}

__global__ __launch_bounds__(256) void k_apply_atomic(
    const float* __restrict__ x,
    const int* __restrict__ srci, const int* __restrict__ tgti,
    const float* __restrict__ W, const float* __restrict__ ab,
    float* __restrict__ out, int E)
{
    const int e = blockIdx.x * 256 + threadIdx.x;
    if (e >= E) return;
    const int s = srci[e], t = tgti[e];
    const float4* ps = (const float4*)(x + (size_t)s * NCH);
    const float4* pt = (const float4*)(x + (size_t)t * NCH);
    float xs[NCH], dx[NCH];
#pragma unroll
    for (int i = 0; i < 8; ++i) {
        float4 a = ps[i], bb = pt[i];
        xs[4*i+0] = a.x; xs[4*i+1] = a.y; xs[4*i+2] = a.z; xs[4*i+3] = a.w;
        dx[4*i+0] = bb.x - a.x; dx[4*i+1] = bb.y - a.y;
        dx[4*i+2] = bb.z - a.z; dx[4*i+3] = bb.w - a.w;
    }
    float* orow = out + (size_t)s * NCH;
#pragma unroll
    for (int c = 0; c < NCH; ++c) {
        const float* wr = W + c * 64;
        float y = 0.f;
#pragma unroll
        for (int k = 0; k < NCH; ++k) y = fmaf(wr[k], xs[k], y);
#pragma unroll
        for (int k = 0; k < NCH; ++k) y = fmaf(wr[32 + k], dx[k], y);
        float z = fmaf(ab[c], y, ab[32 + c]);
        z = (z > 0.f) ? z : (__expf(z) - 1.0f);
        atomicAdd(orow + c, z);
    }
}

// ===========================================================================
extern "C" void kernel_launch(void* const* d_in, const int* in_sizes, int n_in,
                              void* d_out, int out_size, void* d_ws, size_t ws_size,
                              hipStream_t stream)
{
    const float* x     = (const float*)d_in[0];
    const int*   ei    = (const int*)d_in[1];
    const float* W     = (const float*)d_in[2];
    const float* gamma = (const float*)d_in[3];
    const float* beta  = (const float*)d_in[4];
    const int E = in_sizes[1] / 2;
    const int N = in_sizes[0] / NCH;
    const int* srci = ei;
    const int* tgti = ei + E;

    const int NBLK = (E + SLICE - 1) / SLICE;   // edge slices
    const int L    = NBIN * NBLK;               // count matrix size
    const int NBc  = (L + 255) / 256;           // scan blocks
    const int NSB  = (N + NBIN - 1) / NBIN;     // nodes per bin

    // ws layout: uh,vh (bf16) | vq (fp8) | pay (E u32) | cnt (L) | scn (L)
    //            | bsum (NBc) | partials (1024*64 f) | ab (64 f)
    ushort_t* uh  = (ushort_t*)d_ws;
    ushort_t* vh  = uh + (size_t)N * NCH;
    uchar_t*  vq  = (uchar_t*)(vh + (size_t)N * NCH);
    uint_t*   pay = (uint_t*)(vq + (size_t)N * NCH);
    uint_t*   cnt = pay + E;
    uint_t*   scn = cnt + L;
    int*      bsum = (int*)(scn + L);
    float*    partials = (float*)(bsum + NBc);
    float*    ab  = partials + (size_t)1024 * 64;
    const size_t need = (size_t)((char*)(ab + 64) - (char*)d_ws);

    const bool ok = (ws_size >= need) && (NSB <= 256) && (N <= (1 << 17)) &&
                    (NBc <= 1024) && (NBLK >= 1);

    if (ok) {
        k_uv<<<(N + 7) / 8, 256, 0, stream>>>(x, W, uh, vh, vq, N);
        k_count<<<NBLK, 256, 0, stream>>>(srci, cnt, E, NSB);
        k_cbsum<<<NBc, 256, 0, stream>>>(cnt, bsum, L, NBLK);
        k_scan_boff2<<<1, 1024, 0, stream>>>(bsum, NBc);
        k_cwrite<<<NBc, 256, 0, stream>>>(cnt, bsum, scn, L, NBLK);
        k_binscatter<<<NBLK, 256, 0, stream>>>(srci, tgti, scn, pay, E, NSB, NBLK);
        k_stats_bin<<<1024, 256, 0, stream>>>(uh, vq, scn, pay, partials, N, NSB, NBLK, E);
        k_finalize<<<1, 256, 0, stream>>>(partials, 1024, gamma, beta, ab, 1.0f / (float)E);
        k_apply_bin<<<NBIN, 512, 0, stream>>>(uh, vh, scn, pay, ab, (float*)d_out,
                                              N, NSB, NBLK, E);
    } else {
        const int SBf = 512;
        float* abf      = (float*)d_ws;
        float* partialsf = abf + 64;
        hipMemsetAsync(d_out, 0, (size_t)out_size * sizeof(float), stream);
        k_stats_hist<<<SBf, 256, 0, stream>>>(x, srci, tgti, W, partialsf, E);
        k_finalize<<<1, 256, 0, stream>>>(partialsf, SBf, gamma, beta, abf, 1.0f / (float)E);
        k_apply_atomic<<<(E + 255) / 256, 256, 0, stream>>>(x, srci, tgti, W, abf,
                                                            (float*)d_out, E);
    }
}